// Round 7
// baseline (263.539 us; speedup 1.0000x reference)
//
#include <hip/hip_runtime.h>
#include <hip/hip_bf16.h>

#define M_NODES 16384
#define E_EDGES 524288
#define ASTR 68   // uint stride of LDS A rows

typedef short short8 __attribute__((ext_vector_type(8)));
typedef float f32x4 __attribute__((ext_vector_type(4)));
typedef unsigned int uint4v __attribute__((ext_vector_type(4)));

// packed-weight regions (float offsets): [w1 3x4096 | wc 3x4096 | w2 3x4096 | fc1 8192]
#define PK_W1 0
#define PK_WC 12288
#define PK_W2 24576
#define PK_FC1 36864
#define PK_TOTAL 45056

static __device__ __forceinline__ float wredsum(float v) {
#pragma unroll
  for (int o = 32; o > 0; o >>= 1) v += __shfl_xor(v, o, 64);
  return v;
}

static __device__ __forceinline__ float gelu_exact(float x) {
  return 0.5f * x * (1.0f + erff(x * 0.70710678118654752440f));
}

// split fp32 -> (bf16 hi | bf16 lo) packed in one uint
static __device__ __forceinline__ unsigned int bsplit(float x) {
  unsigned int u = __float_as_uint(x);
  unsigned int hb = (u + 0x7FFFu + ((u >> 16) & 1u)) >> 16;
  float hf = __uint_as_float(hb << 16);
  float r = x - hf;
  unsigned int v = __float_as_uint(r);
  unsigned int lb = (v + 0x7FFFu + ((v >> 16) & 1u)) >> 16;
  return (hb & 0xFFFFu) | (lb << 16);
}

struct Frag { short8 hi, lo; };

static __device__ __forceinline__ Frag load_afrag(const unsigned int* a) {
  uint4v u0 = *(const uint4v*)a;
  uint4v u1 = *(const uint4v*)(a + 4);
  Frag f;
#pragma unroll
  for (int j = 0; j < 4; ++j) {
    f.hi[j]     = (short)(u0[j] & 0xFFFFu);
    f.lo[j]     = (short)(u0[j] >> 16);
    f.hi[j + 4] = (short)(u1[j] & 0xFFFFu);
    f.lo[j + 4] = (short)(u1[j] >> 16);
  }
  return f;
}

// raw fp32 weights -> fragments (front kernel init branch only)
static __device__ __forceinline__ Frag load_bfrag(const float* __restrict__ w) {
  float4 w0 = *(const float4*)w;
  float4 w1 = *(const float4*)(w + 4);
  float v[8] = {w0.x, w0.y, w0.z, w0.w, w1.x, w1.y, w1.z, w1.w};
  Frag f;
#pragma unroll
  for (int j = 0; j < 8; ++j) {
    unsigned int p = bsplit(v[j]);
    f.hi[j] = (short)(p & 0xFFFFu);
    f.lo[j] = (short)(p >> 16);
  }
  return f;
}

static __device__ __forceinline__ f32x4 mfma3(const Frag& a, const Frag& b, f32x4 c) {
  c = __builtin_amdgcn_mfma_f32_16x16x32_bf16(a.hi, b.hi, c, 0, 0, 0);
  c = __builtin_amdgcn_mfma_f32_16x16x32_bf16(a.lo, b.hi, c, 0, 0, 0);
  c = __builtin_amdgcn_mfma_f32_16x16x32_bf16(a.hi, b.lo, c, 0, 0, 0);
  return c;
}

// packed-weight B fragment: hi at P[n*64+off], lo at P[S+n*64+off]
static __device__ __forceinline__ Frag load_bpk(const short* __restrict__ P, int S, int n, int off) {
  Frag f;
  f.hi = *(const short8*)(P + n * 64 + off);
  f.lo = *(const short8*)(P + S + n * 64 + off);
  return f;
}

// ---------------------------------------------------------------------------
// front kernel: blocks [0,1024) init; [1024,3072) edge count; [3072,3248) pack
// ---------------------------------------------------------------------------
__global__ __launch_bounds__(256) void k_front(
    const float* __restrict__ x,
    const float* __restrict__ fc0_w, const float* __restrict__ fc0_b,
    const float* __restrict__ ln0_g, const float* __restrict__ ln0_b,
    const float* __restrict__ gg_fc1_w, const float* __restrict__ gg_fc1_b,
    const float* __restrict__ wc_w, const float* __restrict__ wc_b,
    const float* __restrict__ gg_fc2_w, const float* __restrict__ fc1_w,
    const int* __restrict__ ei, int* __restrict__ cnt, short* __restrict__ pk,
    float2* __restrict__ grid2, float* __restrict__ gwf,
    float* __restrict__ hl, float* __restrict__ x2T)
{
  __shared__ unsigned int A[16 * ASTR];
  const int bid = blockIdx.x;
  const int tid = threadIdx.x;

  if (bid >= 3072) {              // ---- pack branch
    int i = (bid - 3072) * 256 + tid;   // [0, 45056)
    float v = (i < PK_WC)  ? gg_fc1_w[i]
            : (i < PK_W2)  ? wc_w[i - PK_WC]
            : (i < PK_FC1) ? gg_fc2_w[i - PK_W2]
                           : fc1_w[i - PK_FC1];
    int mb, sz;
    if (i < PK_FC1) { mb = i & ~4095; sz = 4096; } else { mb = PK_FC1; sz = 8192; }
    int k = i - mb;
    unsigned int p = bsplit(v);
    pk[2 * mb + k]      = (short)(p & 0xFFFFu);
    pk[2 * mb + sz + k] = (short)(p >> 16);
    return;
  }
  if (bid >= 1024) {              // ---- count branch
    int e = (bid - 1024) * 256 + tid;
    atomicAdd(&cnt[ei[E_EDGES + e]], 1);
    return;
  }

  // ---- init branch: 16 nodes/block
  const int lane = tid & 63, w = tid >> 6;
  const int tilebase = bid * 16;

  float fw0 = fc0_w[lane * 4 + 0], fw1 = fc0_w[lane * 4 + 1];
  float fw2v = fc0_w[lane * 4 + 2], fw3 = fc0_w[lane * 4 + 3];
  float fb = fc0_b[lane], g0 = ln0_g[lane], bb0 = ln0_b[lane];

#pragma unroll
  for (int i = 0; i < 4; ++i) {
    int node = tilebase + 4 * w + i;
    float xv0 = x[node * 5 + 0], xv1 = x[node * 5 + 1], xv2 = x[node * 5 + 2];
    float xv3 = x[node * 5 + 3], xv4 = x[node * 5 + 4];
    float acc = fb + xv0 * fw0 + xv1 * fw1 + xv2 * fw2v + xv3 * fw3;
    float mean = wredsum(acc) * (1.0f / 64.0f);
    float d = acc - mean;
    float var = wredsum(d * d) * (1.0f / 64.0f);
    float hv = d * rsqrtf(var + 1e-5f) * g0 + bb0;
    A[(4 * w + i) * ASTR + lane] = bsplit(hv);
    if (lane == 0) { grid2[node] = make_float2(xv2, xv3); gwf[node] = xv4; }
  }
  __syncthreads();

  const int c = lane & 15, q = lane >> 4;
  const int n = 16 * w + c;

  {
    Frag a0 = load_afrag(A + c * ASTR + 8 * q);
    Frag a1 = load_afrag(A + c * ASTR + 32 + 8 * q);
    Frag b0 = load_bfrag(gg_fc1_w + n * 64 + 8 * q);
    Frag b1 = load_bfrag(gg_fc1_w + n * 64 + 32 + 8 * q);
    f32x4 acc = {0.f, 0.f, 0.f, 0.f};
    acc = mfma3(a0, b0, acc);
    acc = mfma3(a1, b1, acc);
    float b1v = gg_fc1_b[n];
#pragma unroll
    for (int r = 0; r < 4; ++r)
      hl[(tilebase + 4 * q + r) * 64 + n] = acc[r] + b1v;

    Frag c0 = load_bfrag(wc_w + n * 64 + 8 * q);
    Frag c1 = load_bfrag(wc_w + n * 64 + 32 + 8 * q);
    f32x4 ac2 = {0.f, 0.f, 0.f, 0.f};
    ac2 = mfma3(a0, c0, ac2);
    ac2 = mfma3(a1, c1, ac2);
    float wcbv = wc_b[n];
    *(float4*)(x2T + n * M_NODES + tilebase + 4 * q) =
        make_float4(ac2[0] + wcbv, ac2[1] + wcbv, ac2[2] + wcbv, ac2[3] + wcbv);
  }
}

// ---------------------------------------------------------------------------
__global__ __launch_bounds__(1024) void k_scan(const int* __restrict__ cnt,
                                               int* __restrict__ row_start,
                                               int* __restrict__ cursor)
{
  const int PER = M_NODES / 1024;
  const int t = threadIdx.x;
  const int base = t * PER;
  int local[PER];
  int s = 0;
#pragma unroll
  for (int k = 0; k < PER; ++k) { local[k] = cnt[base + k]; s += local[k]; }

  __shared__ int part[1024];
  part[t] = s;
  __syncthreads();
  for (int off = 1; off < 1024; off <<= 1) {
    int v = (t >= off) ? part[t - off] : 0;
    __syncthreads();
    part[t] += v;
    __syncthreads();
  }
  int run = part[t] - s;
#pragma unroll
  for (int k = 0; k < PER; ++k) {
    row_start[base + k] = run;
    cursor[base + k] = run;
    run += local[k];
  }
  if (t == 1023) row_start[M_NODES] = run;
}

__global__ __launch_bounds__(256) void k_scatter(
    const int* __restrict__ ei, const float2* __restrict__ grid2,
    const float* __restrict__ gwf, int* __restrict__ cursor,
    float4* __restrict__ rec)
{
  int e = blockIdx.x * 256 + threadIdx.x;
  if (e < E_EDGES) {
    int s = ei[e];
    int dd = ei[E_EDGES + e];
    int pos = atomicAdd(&cursor[dd], 1);
    float2 gs = grid2[s], gd = grid2[dd];
    rec[pos] = make_float4(gs.x - gd.x, gs.y - gd.y, gwf[s], __int_as_float(s));
  }
}

// ---------------------------------------------------------------------------
// EDGE_PHASE macro body (shared by both fused layer kernels):
// wave w aggregates its 4 nodes' edges into packed LDS rows of A.
// rec read via wave-uniform global loads (1 L1 transaction each, no LDS pipe);
// hl gathered coalesced 256B; 8-deep ping-pong for MLP.
// ---------------------------------------------------------------------------
#define EDGE_PHASE()                                                          \
  const float wv = gw[lane];                                                  \
  const float nwl2 = -wv * 1.44269504088896340736f;                           \
  const float lc = log2f(wv * 0.31830988618379067154f);                       \
  const float f0s = freq[lane] * 0.15915494309189533577f;                     \
  const float f1s = freq[64 + lane] * 0.15915494309189533577f;                \
  const float* hlp = hl_in + lane;                                            \
  for (int nn = 0; nn < 4; ++nn) {                                            \
    const int node = tilebase + 4 * w + nn;                                   \
    const int beg = row_start[node];                                          \
    const int cn = row_start[node + 1] - beg;                                 \
    float acc = 0.f;                                                          \
    if (cn > 0) {                                                             \
      float4 RA[8], RB[8]; float HA[8], HB[8];                                \
      auto ldg = [&](float4* R, float* H, int off) {                          \
        _Pragma("unroll")                                                     \
        for (int u = 0; u < 8; ++u) {                                         \
          int j = off + u; j = (j < cn) ? j : (cn - 1);                       \
          R[u] = rec[beg + j];                                                \
        }                                                                     \
        _Pragma("unroll")                                                     \
        for (int u = 0; u < 8; ++u)                                           \
          H[u] = hlp[__float_as_int(R[u].w) * 64];                            \
      };                                                                      \
      auto cmp8 = [&](const float4* R, const float* H, int off) {             \
        _Pragma("unroll")                                                     \
        for (int u = 0; u < 8; ++u) {                                         \
          if (off + u < cn) {                                                 \
            float dist2 = __builtin_fmaf(R[u].x, R[u].x, R[u].y * R[u].y);    \
            float gs = __builtin_amdgcn_exp2f(__builtin_fmaf(nwl2, dist2, lc));\
            float rev = __builtin_fmaf(R[u].x, f0s, R[u].y * f1s);            \
            float fo = __builtin_amdgcn_sinf(__builtin_amdgcn_fractf(rev));   \
            acc = __builtin_fmaf(gs * fo * H[u], R[u].z, acc);                \
          }                                                                   \
        }                                                                     \
      };                                                                      \
      const int Gp = (cn + 7) >> 3;                                           \
      ldg(RA, HA, 0);                                                         \
      int g = 0;                                                              \
      for (; g + 2 < Gp; g += 2) {                                            \
        ldg(RB, HB, 8 * (g + 1));                                             \
        cmp8(RA, HA, 8 * g);                                                  \
        ldg(RA, HA, 8 * (g + 2));                                             \
        cmp8(RB, HB, 8 * (g + 1));                                            \
      }                                                                       \
      if (g + 1 < Gp) {                                                       \
        ldg(RB, HB, 8 * (g + 1));                                             \
        cmp8(RA, HA, 8 * g);                                                  \
        cmp8(RB, HB, 8 * (g + 1));                                            \
      } else {                                                                \
        cmp8(RA, HA, 8 * g);                                                  \
      }                                                                       \
    }                                                                         \
    A[(4 * w + nn) * ASTR + lane] = bsplit(acc);                              \
  }

// ---------------------------------------------------------------------------
// fused layer (0,1): edge agg -> S = agg@W2.T + b2 + x2 -> h = gelu(LN(S))
// -> hl_out = h@W1n.T + b1n ; x2T = h@Wcn.T + wcbn
// ---------------------------------------------------------------------------
__global__ __launch_bounds__(256) void k_layer_mid(
    const float4* __restrict__ rec, const int* __restrict__ row_start,
    const float* __restrict__ hl_in,
    const float* __restrict__ gw, const float* __restrict__ freq,
    const short* __restrict__ pw2, const float* __restrict__ b2,
    const float* __restrict__ lng, const float* __restrict__ lnb,
    const short* __restrict__ pnw1, const float* __restrict__ nb1,
    const short* __restrict__ pnwc, const float* __restrict__ nwcb,
    float* __restrict__ hl_out, float* __restrict__ x2T)
{
  __shared__ unsigned int A[16 * ASTR];
  __shared__ float PS[4][16], PQ[4][16];
  const int tid = threadIdx.x, lane = tid & 63, w = tid >> 6;
  const int tilebase = blockIdx.x * 16;
  const int c = lane & 15, q = lane >> 4;
  const int n = 16 * w + c;

  // early prefetches (cheap regs, long latency hidden behind edge phase)
  float4 x2v = *(const float4*)(x2T + n * M_NODES + tilebase + 4 * q);
  float lg = lng[n], lb = lnb[n], vb = b2[n];
  float b1v = nb1[n], wcbv = nwcb[n];

  EDGE_PHASE()

  // weight frags issued while waiting on barrier
  Frag wb0 = load_bpk(pw2, 4096, n, 8 * q);
  Frag wb1 = load_bpk(pw2, 4096, n, 32 + 8 * q);
  Frag n10 = load_bpk(pnw1, 4096, n, 8 * q);
  Frag n11 = load_bpk(pnw1, 4096, n, 32 + 8 * q);
  Frag nc0 = load_bpk(pnwc, 4096, n, 8 * q);
  Frag nc1 = load_bpk(pnwc, 4096, n, 32 + 8 * q);
  __syncthreads();

  Frag a0 = load_afrag(A + c * ASTR + 8 * q);
  Frag a1 = load_afrag(A + c * ASTR + 32 + 8 * q);
  f32x4 acc = {0.f, 0.f, 0.f, 0.f};
  acc = mfma3(a0, wb0, acc);
  acc = mfma3(a1, wb1, acc);

  float S[4];
#pragma unroll
  for (int r = 0; r < 4; ++r) S[r] = acc[r] + vb + x2v[r];

#pragma unroll
  for (int r = 0; r < 4; ++r) {
    float s1 = S[r], s2 = S[r] * S[r];
#pragma unroll
    for (int m = 1; m < 16; m <<= 1) {
      s1 += __shfl_xor(s1, m, 64);
      s2 += __shfl_xor(s2, m, 64);
    }
    if (c == 0) { PS[w][4 * q + r] = s1; PQ[w][4 * q + r] = s2; }
  }
  __syncthreads();

#pragma unroll
  for (int r = 0; r < 4; ++r) {
    int row = 4 * q + r;
    float sum = PS[0][row] + PS[1][row] + PS[2][row] + PS[3][row];
    float sq  = PQ[0][row] + PQ[1][row] + PQ[2][row] + PQ[3][row];
    float mean = sum * (1.0f / 64.0f);
    float var = sq * (1.0f / 64.0f) - mean * mean;
    float hv = (S[r] - mean) * rsqrtf(var + 1e-5f) * lg + lb;
    hv = gelu_exact(hv);
    A[row * ASTR + n] = bsplit(hv);
  }
  __syncthreads();   // h fully written before cross-wave GEMM reads

  Frag h0 = load_afrag(A + c * ASTR + 8 * q);
  Frag h1 = load_afrag(A + c * ASTR + 32 + 8 * q);

  f32x4 hh = {0.f, 0.f, 0.f, 0.f};
  hh = mfma3(h0, n10, hh);
  hh = mfma3(h1, n11, hh);
#pragma unroll
  for (int r = 0; r < 4; ++r)
    hl_out[(tilebase + 4 * q + r) * 64 + n] = hh[r] + b1v;

  f32x4 hx = {0.f, 0.f, 0.f, 0.f};
  hx = mfma3(h0, nc0, hx);
  hx = mfma3(h1, nc1, hx);
  *(float4*)(x2T + n * M_NODES + tilebase + 4 * q) =
      make_float4(hx[0] + wcbv, hx[1] + wcbv, hx[2] + wcbv, hx[3] + wcbv);
}

// ---------------------------------------------------------------------------
// fused layer 2 + head: edge agg -> h = LN(S) -> t = gelu(h@fc1.T+b) -> out
// ---------------------------------------------------------------------------
__global__ __launch_bounds__(256) void k_layer_last(
    const float4* __restrict__ rec, const int* __restrict__ row_start,
    const float* __restrict__ hl_in,
    const float* __restrict__ gw, const float* __restrict__ freq,
    const short* __restrict__ pw2, const float* __restrict__ b2,
    const float* __restrict__ lng, const float* __restrict__ lnb,
    const float* __restrict__ x2T,
    const short* __restrict__ pfc1, const float* __restrict__ fc1b,
    const float* __restrict__ fw2, const float* __restrict__ fb2,
    float* __restrict__ out)
{
  __shared__ unsigned int A[16 * ASTR];
  __shared__ float PS[4][16], PQ[4][16];
  const int tid = threadIdx.x, lane = tid & 63, w = tid >> 6;
  const int tilebase = blockIdx.x * 16;
  const int c = lane & 15, q = lane >> 4;
  const int n = 16 * w + c;

  float4 x2v = *(const float4*)(x2T + n * M_NODES + tilebase + 4 * q);
  float lg = lng[n], lb = lnb[n], vb = b2[n];

  EDGE_PHASE()

  Frag wb0 = load_bpk(pw2, 4096, n, 8 * q);
  Frag wb1 = load_bpk(pw2, 4096, n, 32 + 8 * q);
  __syncthreads();

  Frag a0 = load_afrag(A + c * ASTR + 8 * q);
  Frag a1 = load_afrag(A + c * ASTR + 32 + 8 * q);
  f32x4 acc = {0.f, 0.f, 0.f, 0.f};
  acc = mfma3(a0, wb0, acc);
  acc = mfma3(a1, wb1, acc);

  float S[4];
#pragma unroll
  for (int r = 0; r < 4; ++r) S[r] = acc[r] + vb + x2v[r];

#pragma unroll
  for (int r = 0; r < 4; ++r) {
    float s1 = S[r], s2 = S[r] * S[r];
#pragma unroll
    for (int m = 1; m < 16; m <<= 1) {
      s1 += __shfl_xor(s1, m, 64);
      s2 += __shfl_xor(s2, m, 64);
    }
    if (c == 0) { PS[w][4 * q + r] = s1; PQ[w][4 * q + r] = s2; }
  }
  __syncthreads();

#pragma unroll
  for (int r = 0; r < 4; ++r) {
    int row = 4 * q + r;
    float sum = PS[0][row] + PS[1][row] + PS[2][row] + PS[3][row];
    float sq  = PQ[0][row] + PQ[1][row] + PQ[2][row] + PQ[3][row];
    float mean = sum * (1.0f / 64.0f);
    float var = sq * (1.0f / 64.0f) - mean * mean;
    float hv = (S[r] - mean) * rsqrtf(var + 1e-5f) * lg + lb;   // no gelu
    A[row * ASTR + n] = bsplit(hv);
  }
  __syncthreads();

  // head: wave w covers fc1 rows 32w + {c, 16+c}
  Frag ha0 = load_afrag(A + c * ASTR + 8 * q);
  Frag ha1 = load_afrag(A + c * ASTR + 32 + 8 * q);
  float p[4] = {0.f, 0.f, 0.f, 0.f};
#pragma unroll
  for (int half = 0; half < 2; ++half) {
    int row = 32 * w + 16 * half + c;
    Frag b0 = load_bpk(pfc1, 8192, row, 8 * q);
    Frag b1 = load_bpk(pfc1, 8192, row, 32 + 8 * q);
    f32x4 a = {0.f, 0.f, 0.f, 0.f};
    a = mfma3(ha0, b0, a);
    a = mfma3(ha1, b1, a);
    float fbv = fc1b[row], fwv = fw2[row];
#pragma unroll
    for (int r = 0; r < 4; ++r) p[r] += gelu_exact(a[r] + fbv) * fwv;
  }
#pragma unroll
  for (int r = 0; r < 4; ++r) {
    float s = p[r];
#pragma unroll
    for (int m = 1; m < 16; m <<= 1) s += __shfl_xor(s, m, 64);
    if (c == 0) PS[w][4 * q + r] = s;
  }
  __syncthreads();
  if (tid < 16)
    out[tilebase + tid] = PS[0][tid] + PS[1][tid] + PS[2][tid] + PS[3][tid] + fb2[0];
}

// ---------------------------------------------------------------------------
extern "C" void kernel_launch(void* const* d_in, const int* in_sizes, int n_in,
                              void* d_out, int out_size, void* d_ws, size_t ws_size,
                              hipStream_t stream) {
  const float* x     = (const float*)d_in[0];
  const int* ei      = (const int*)d_in[1];
  const float* fc0_w = (const float*)d_in[2];
  const float* fc0_b = (const float*)d_in[3];
  const float* ln0_g = (const float*)d_in[4];
  const float* ln0_b = (const float*)d_in[5];
  const float* gg_fc1_w = (const float*)d_in[6];
  const float* gg_fc1_b = (const float*)d_in[7];
  const float* gg_fc2_w = (const float*)d_in[8];
  const float* gg_fc2_b = (const float*)d_in[9];
  const float* gg_weight = (const float*)d_in[10];
  const float* gg_freq   = (const float*)d_in[11];
  const float* wc_w = (const float*)d_in[12];
  const float* wc_b = (const float*)d_in[13];
  const float* ln_g = (const float*)d_in[14];
  const float* ln_b = (const float*)d_in[15];
  const float* fc1_w = (const float*)d_in[16];
  const float* fc1_b = (const float*)d_in[17];
  const float* fc2_w = (const float*)d_in[18];
  const float* fc2_b = (const float*)d_in[19];

  char* ws = (char*)d_ws;
  size_t off = 0;
  auto alloc = [&](size_t bytes) -> void* {
    void* p = ws + off;
    off = (off + bytes + 255) & ~(size_t)255;
    return p;
  };
  float2* grid2 = (float2*)alloc((size_t)M_NODES * 8);
  float*  gwf   = (float*)alloc((size_t)M_NODES * 4);
  float*  hl_a  = (float*)alloc((size_t)M_NODES * 64 * 4);
  float*  hl_b  = (float*)alloc((size_t)M_NODES * 64 * 4);
  float*  x2T   = (float*)alloc((size_t)M_NODES * 64 * 4);
  int*    cnt   = (int*)alloc((size_t)M_NODES * 4);
  int*    cursor= (int*)alloc((size_t)M_NODES * 4);
  int*    row_st= (int*)alloc((size_t)(M_NODES + 1) * 4);
  float4* rec   = (float4*)alloc((size_t)E_EDGES * 16);
  short*  pk    = (short*)alloc((size_t)PK_TOTAL * 2 * 2);
  (void)ws_size; (void)in_sizes; (void)n_in; (void)out_size;

  hipMemsetAsync(cnt, 0, (size_t)M_NODES * 4, stream);

  k_front<<<3248, 256, 0, stream>>>(x, fc0_w, fc0_b, ln0_g, ln0_b,
                                    gg_fc1_w, gg_fc1_b, wc_w, wc_b,
                                    gg_fc2_w, fc1_w,
                                    ei, cnt, pk, grid2, gwf, hl_a, x2T);
  k_scan<<<1, 1024, 0, stream>>>(cnt, row_st, cursor);
  k_scatter<<<E_EDGES / 256, 256, 0, stream>>>(ei, grid2, gwf, cursor, rec);

  // layer 0: read hl_a -> write hl_b
  k_layer_mid<<<M_NODES / 16, 256, 0, stream>>>(
      rec, row_st, hl_a, gg_weight + 0 * 64, gg_freq + 0 * 128,
      pk + 2 * (PK_W2 + 0 * 4096), gg_fc2_b + 0 * 64,
      ln_g + 0 * 64, ln_b + 0 * 64,
      pk + 2 * (PK_W1 + 1 * 4096), gg_fc1_b + 1 * 64,
      pk + 2 * (PK_WC + 1 * 4096), wc_b + 1 * 64,
      hl_b, x2T);
  // layer 1: read hl_b -> write hl_a
  k_layer_mid<<<M_NODES / 16, 256, 0, stream>>>(
      rec, row_st, hl_b, gg_weight + 1 * 64, gg_freq + 1 * 128,
      pk + 2 * (PK_W2 + 1 * 4096), gg_fc2_b + 1 * 64,
      ln_g + 1 * 64, ln_b + 1 * 64,
      pk + 2 * (PK_W1 + 2 * 4096), gg_fc1_b + 2 * 64,
      pk + 2 * (PK_WC + 2 * 4096), wc_b + 2 * 64,
      hl_a, x2T);
  // layer 2 + head: read hl_a -> out
  k_layer_last<<<M_NODES / 16, 256, 0, stream>>>(
      rec, row_st, hl_a, gg_weight + 2 * 64, gg_freq + 2 * 128,
      pk + 2 * (PK_W2 + 2 * 4096), gg_fc2_b + 2 * 64,
      ln_g + 2 * 64, ln_b + 2 * 64,
      x2T,
      pk + 2 * PK_FC1, fc1_b, fc2_w, fc2_b,
      (float*)d_out);
}

// Round 8
// 251.867 us; speedup vs baseline: 1.0463x; 1.0463x over previous
//
#include <hip/hip_runtime.h>
#include <hip/hip_bf16.h>

#define M_NODES 16384
#define E_EDGES 524288
#define ASTR 68   // uint stride of LDS A rows

typedef short short8 __attribute__((ext_vector_type(8)));
typedef float f32x4 __attribute__((ext_vector_type(4)));
typedef unsigned int uint4v __attribute__((ext_vector_type(4)));

// packed-weight regions (float offsets): [w1 3x4096 | wc 3x4096 | w2 3x4096 | fc1 8192]
#define PK_W1 0
#define PK_WC 12288
#define PK_W2 24576
#define PK_FC1 36864
#define PK_TOTAL 45056

static __device__ __forceinline__ float wredsum(float v) {
#pragma unroll
  for (int o = 32; o > 0; o >>= 1) v += __shfl_xor(v, o, 64);
  return v;
}

static __device__ __forceinline__ float gelu_exact(float x) {
  return 0.5f * x * (1.0f + erff(x * 0.70710678118654752440f));
}

// split fp32 -> (bf16 hi | bf16 lo) packed in one uint
static __device__ __forceinline__ unsigned int bsplit(float x) {
  unsigned int u = __float_as_uint(x);
  unsigned int hb = (u + 0x7FFFu + ((u >> 16) & 1u)) >> 16;
  float hf = __uint_as_float(hb << 16);
  float r = x - hf;
  unsigned int v = __float_as_uint(r);
  unsigned int lb = (v + 0x7FFFu + ((v >> 16) & 1u)) >> 16;
  return (hb & 0xFFFFu) | (lb << 16);
}

struct Frag { short8 hi, lo; };

static __device__ __forceinline__ Frag load_afrag(const unsigned int* a) {
  uint4v u0 = *(const uint4v*)a;
  uint4v u1 = *(const uint4v*)(a + 4);
  Frag f;
#pragma unroll
  for (int j = 0; j < 4; ++j) {
    f.hi[j]     = (short)(u0[j] & 0xFFFFu);
    f.lo[j]     = (short)(u0[j] >> 16);
    f.hi[j + 4] = (short)(u1[j] & 0xFFFFu);
    f.lo[j + 4] = (short)(u1[j] >> 16);
  }
  return f;
}

// raw fp32 weights -> fragments (front kernel init branch only)
static __device__ __forceinline__ Frag load_bfrag(const float* __restrict__ w) {
  float4 w0 = *(const float4*)w;
  float4 w1 = *(const float4*)(w + 4);
  float v[8] = {w0.x, w0.y, w0.z, w0.w, w1.x, w1.y, w1.z, w1.w};
  Frag f;
#pragma unroll
  for (int j = 0; j < 8; ++j) {
    unsigned int p = bsplit(v[j]);
    f.hi[j] = (short)(p & 0xFFFFu);
    f.lo[j] = (short)(p >> 16);
  }
  return f;
}

static __device__ __forceinline__ f32x4 mfma3(const Frag& a, const Frag& b, f32x4 c) {
  c = __builtin_amdgcn_mfma_f32_16x16x32_bf16(a.hi, b.hi, c, 0, 0, 0);
  c = __builtin_amdgcn_mfma_f32_16x16x32_bf16(a.lo, b.hi, c, 0, 0, 0);
  c = __builtin_amdgcn_mfma_f32_16x16x32_bf16(a.hi, b.lo, c, 0, 0, 0);
  return c;
}

// packed-weight B fragment: hi at P[n*64+off], lo at P[S+n*64+off]
static __device__ __forceinline__ Frag load_bpk(const short* __restrict__ P, int S, int n, int off) {
  Frag f;
  f.hi = *(const short8*)(P + n * 64 + off);
  f.lo = *(const short8*)(P + S + n * 64 + off);
  return f;
}

static __device__ __forceinline__ float rdlanef(float v, int j) {
  return __int_as_float(__builtin_amdgcn_readlane(__float_as_int(v), j));
}

// ---------------------------------------------------------------------------
// front kernel: blocks [0,1024) init; [1024,3072) edge count; [3072,3248) pack
// ---------------------------------------------------------------------------
__global__ __launch_bounds__(256) void k_front(
    const float* __restrict__ x,
    const float* __restrict__ fc0_w, const float* __restrict__ fc0_b,
    const float* __restrict__ ln0_g, const float* __restrict__ ln0_b,
    const float* __restrict__ gg_fc1_w, const float* __restrict__ gg_fc1_b,
    const float* __restrict__ wc_w, const float* __restrict__ wc_b,
    const float* __restrict__ gg_fc2_w, const float* __restrict__ fc1_w,
    const int* __restrict__ ei, int* __restrict__ cnt, short* __restrict__ pk,
    float2* __restrict__ grid2, float* __restrict__ gwf,
    float* __restrict__ hlf, float* __restrict__ x2T)
{
  __shared__ unsigned int A[16 * ASTR];
  const int bid = blockIdx.x;
  const int tid = threadIdx.x;

  if (bid >= 3072) {              // ---- pack branch
    int i = (bid - 3072) * 256 + tid;   // [0, 45056)
    float v = (i < PK_WC)  ? gg_fc1_w[i]
            : (i < PK_W2)  ? wc_w[i - PK_WC]
            : (i < PK_FC1) ? gg_fc2_w[i - PK_W2]
                           : fc1_w[i - PK_FC1];
    int mb, sz;
    if (i < PK_FC1) { mb = i & ~4095; sz = 4096; } else { mb = PK_FC1; sz = 8192; }
    int k = i - mb;
    unsigned int p = bsplit(v);
    pk[2 * mb + k]      = (short)(p & 0xFFFFu);
    pk[2 * mb + sz + k] = (short)(p >> 16);
    return;
  }
  if (bid >= 1024) {              // ---- count branch
    int e = (bid - 1024) * 256 + tid;
    atomicAdd(&cnt[ei[E_EDGES + e]], 1);
    return;
  }

  // ---- init branch: 16 nodes/block
  const int lane = tid & 63, w = tid >> 6;
  const int tilebase = bid * 16;

  float fw0 = fc0_w[lane * 4 + 0], fw1 = fc0_w[lane * 4 + 1];
  float fw2v = fc0_w[lane * 4 + 2], fw3 = fc0_w[lane * 4 + 3];
  float fb = fc0_b[lane], g0 = ln0_g[lane], bb0 = ln0_b[lane];

#pragma unroll
  for (int i = 0; i < 4; ++i) {
    int node = tilebase + 4 * w + i;
    float xv0 = x[node * 5 + 0], xv1 = x[node * 5 + 1], xv2 = x[node * 5 + 2];
    float xv3 = x[node * 5 + 3], xv4 = x[node * 5 + 4];
    float acc = fb + xv0 * fw0 + xv1 * fw1 + xv2 * fw2v + xv3 * fw3;
    float mean = wredsum(acc) * (1.0f / 64.0f);
    float d = acc - mean;
    float var = wredsum(d * d) * (1.0f / 64.0f);
    float hv = d * rsqrtf(var + 1e-5f) * g0 + bb0;
    A[(4 * w + i) * ASTR + lane] = bsplit(hv);
    if (lane == 0) { grid2[node] = make_float2(xv2, xv3); gwf[node] = xv4; }
  }
  __syncthreads();

  const int c = lane & 15, q = lane >> 4;
  const int n = 16 * w + c;

  {
    Frag a0 = load_afrag(A + c * ASTR + 8 * q);
    Frag a1 = load_afrag(A + c * ASTR + 32 + 8 * q);
    Frag b0 = load_bfrag(gg_fc1_w + n * 64 + 8 * q);
    Frag b1 = load_bfrag(gg_fc1_w + n * 64 + 32 + 8 * q);
    f32x4 acc = {0.f, 0.f, 0.f, 0.f};
    acc = mfma3(a0, b0, acc);
    acc = mfma3(a1, b1, acc);
    float b1v = gg_fc1_b[n];
#pragma unroll
    for (int r = 0; r < 4; ++r) {
      float gwr = x[(tilebase + 4 * q + r) * 5 + 4];       // gwf of row node
      hlf[(tilebase + 4 * q + r) * 64 + n] = (acc[r] + b1v) * gwr;   // wgt folded
    }

    Frag c0 = load_bfrag(wc_w + n * 64 + 8 * q);
    Frag c1 = load_bfrag(wc_w + n * 64 + 32 + 8 * q);
    f32x4 ac2 = {0.f, 0.f, 0.f, 0.f};
    ac2 = mfma3(a0, c0, ac2);
    ac2 = mfma3(a1, c1, ac2);
    float wcbv = wc_b[n];
    *(float4*)(x2T + n * M_NODES + tilebase + 4 * q) =
        make_float4(ac2[0] + wcbv, ac2[1] + wcbv, ac2[2] + wcbv, ac2[3] + wcbv);
  }
}

// ---------------------------------------------------------------------------
__global__ __launch_bounds__(1024) void k_scan(const int* __restrict__ cnt,
                                               int* __restrict__ row_start,
                                               int* __restrict__ cursor,
                                               int* __restrict__ esrc,
                                               float2* __restrict__ evw)
{
  const int PER = M_NODES / 1024;
  const int t = threadIdx.x;
  const int base = t * PER;
  int local[PER];
  int s = 0;
#pragma unroll
  for (int k = 0; k < PER; ++k) { local[k] = cnt[base + k]; s += local[k]; }

  __shared__ int part[1024];
  part[t] = s;
  __syncthreads();
  for (int off = 1; off < 1024; off <<= 1) {
    int v = (t >= off) ? part[t - off] : 0;
    __syncthreads();
    part[t] += v;
    __syncthreads();
  }
  int run = part[t] - s;
#pragma unroll
  for (int k = 0; k < PER; ++k) {
    row_start[base + k] = run;
    cursor[base + k] = run;
    run += local[k];
  }
  if (t == 1023) row_start[M_NODES] = run;
  if (t == 0) { esrc[E_EDGES] = 0; evw[E_EDGES] = make_float2(0.f, 0.f); }  // dummy: 0-contribution
}

__global__ __launch_bounds__(256) void k_scatter(
    const int* __restrict__ ei, const float2* __restrict__ grid2,
    int* __restrict__ cursor,
    int* __restrict__ esrc, float2* __restrict__ evw)
{
  int e = blockIdx.x * 256 + threadIdx.x;
  if (e < E_EDGES) {
    int s = ei[e];
    int dd = ei[E_EDGES + e];
    int pos = atomicAdd(&cursor[dd], 1);
    float2 gs = grid2[s], gd = grid2[dd];
    esrc[pos] = s;
    evw[pos] = make_float2(gs.x - gd.x, gs.y - gd.y);
  }
}

// ---------------------------------------------------------------------------
// EDGE_PHASE: per-wave node aggregation.
// Per 64-edge chunk: 2 coalesced loads (esrc, evw) -> per-edge scalars
// broadcast via v_readlane (register, no memory) -> gathers issue with no
// serial rec latency; 8-group ping-pong; tail padded by dummy edge (sin(0)=0).
// wgt_src is pre-folded into hlf.
// ---------------------------------------------------------------------------
#define EDGE_PHASE()                                                          \
  const float wv = gw[lane];                                                  \
  const float nwl2 = -wv * 1.44269504088896340736f;                           \
  const float lc = log2f(wv * 0.31830988618379067154f);                       \
  const float f0s = freq[lane] * 0.15915494309189533577f;                     \
  const float f1s = freq[64 + lane] * 0.15915494309189533577f;                \
  const float* __restrict__ hrow = hlf_in + lane;                             \
  for (int nn = 0; nn < 4; ++nn) {                                            \
    const int node = tilebase + 4 * w + nn;                                   \
    const int beg = row_start[node];                                          \
    const int end = row_start[node + 1];                                      \
    float acc = 0.f;                                                          \
    for (int cb = beg; cb < end; cb += 64) {                                  \
      const int cnc = min(64, end - cb);                                      \
      const int idx = (lane < cnc) ? (cb + lane) : E_EDGES;                   \
      const int src_l = esrc[idx];                                            \
      const float2 v_l = evw[idx];                                            \
      const float d2_l = __builtin_fmaf(v_l.x, v_l.x, v_l.y * v_l.y);         \
      float HA[8], HB[8];                                                     \
      auto g8 = [&](float* H, int g) {                                        \
        _Pragma("unroll")                                                     \
        for (int u = 0; u < 8; ++u) {                                         \
          int ss = __builtin_amdgcn_readlane(src_l, 8 * g + u);               \
          H[u] = hrow[(size_t)ss * 64];                                       \
        }                                                                     \
      };                                                                      \
      auto c8 = [&](const float* H, int g) {                                  \
        _Pragma("unroll")                                                     \
        for (int u = 0; u < 8; ++u) {                                         \
          int j = 8 * g + u;                                                  \
          float svx = rdlanef(v_l.x, j);                                      \
          float svy = rdlanef(v_l.y, j);                                      \
          float sd2 = rdlanef(d2_l, j);                                       \
          float ga = __builtin_amdgcn_exp2f(__builtin_fmaf(nwl2, sd2, lc));   \
          float rv = __builtin_fmaf(svx, f0s, svy * f1s);                     \
          float fo = __builtin_amdgcn_sinf(__builtin_amdgcn_fractf(rv));      \
          acc = __builtin_fmaf(ga * fo, H[u], acc);                           \
        }                                                                     \
      };                                                                      \
      const int Gp = (cnc + 7) >> 3;                                          \
      g8(HA, 0);                                                              \
      int g = 0;                                                              \
      for (; g + 2 < Gp; g += 2) {                                            \
        g8(HB, g + 1);                                                        \
        c8(HA, g);                                                            \
        g8(HA, g + 2);                                                        \
        c8(HB, g + 1);                                                        \
      }                                                                       \
      if (g + 1 < Gp) {                                                       \
        g8(HB, g + 1);                                                        \
        c8(HA, g);                                                            \
        c8(HB, g + 1);                                                        \
      } else {                                                                \
        c8(HA, g);                                                            \
      }                                                                       \
    }                                                                         \
    A[(4 * w + nn) * ASTR + lane] = bsplit(acc);                              \
  }

// ---------------------------------------------------------------------------
// fused layer (0,1): edge agg -> S = agg@W2.T + b2 + x2 -> h = gelu(LN(S))
// -> hlf_out = (h@W1n.T + b1n)*gwf ; x2T = h@Wcn.T + wcbn
// ---------------------------------------------------------------------------
__global__ __launch_bounds__(256) void k_layer_mid(
    const int* __restrict__ esrc, const float2* __restrict__ evw,
    const int* __restrict__ row_start,
    const float* __restrict__ hlf_in, const float* __restrict__ gwf,
    const float* __restrict__ gw, const float* __restrict__ freq,
    const short* __restrict__ pw2, const float* __restrict__ b2,
    const float* __restrict__ lng, const float* __restrict__ lnb,
    const short* __restrict__ pnw1, const float* __restrict__ nb1,
    const short* __restrict__ pnwc, const float* __restrict__ nwcb,
    float* __restrict__ hlf_out, float* __restrict__ x2T)
{
  __shared__ unsigned int A[16 * ASTR];
  __shared__ float PS[4][16], PQ[4][16];
  const int tid = threadIdx.x, lane = tid & 63, w = tid >> 6;
  const int tilebase = blockIdx.x * 16;
  const int c = lane & 15, q = lane >> 4;
  const int n = 16 * w + c;

  // early prefetches
  float4 x2v = *(const float4*)(x2T + n * M_NODES + tilebase + 4 * q);
  float4 gw4 = *(const float4*)(gwf + tilebase + 4 * q);
  float lg = lng[n], lb = lnb[n], vb = b2[n];
  float b1v = nb1[n], wcbv = nwcb[n];

  EDGE_PHASE()

  Frag wb0 = load_bpk(pw2, 4096, n, 8 * q);
  Frag wb1 = load_bpk(pw2, 4096, n, 32 + 8 * q);
  Frag n10 = load_bpk(pnw1, 4096, n, 8 * q);
  Frag n11 = load_bpk(pnw1, 4096, n, 32 + 8 * q);
  Frag nc0 = load_bpk(pnwc, 4096, n, 8 * q);
  Frag nc1 = load_bpk(pnwc, 4096, n, 32 + 8 * q);
  __syncthreads();

  Frag a0 = load_afrag(A + c * ASTR + 8 * q);
  Frag a1 = load_afrag(A + c * ASTR + 32 + 8 * q);
  f32x4 acc = {0.f, 0.f, 0.f, 0.f};
  acc = mfma3(a0, wb0, acc);
  acc = mfma3(a1, wb1, acc);

  float S[4];
#pragma unroll
  for (int r = 0; r < 4; ++r) S[r] = acc[r] + vb + x2v[r];

#pragma unroll
  for (int r = 0; r < 4; ++r) {
    float s1 = S[r], s2 = S[r] * S[r];
#pragma unroll
    for (int m = 1; m < 16; m <<= 1) {
      s1 += __shfl_xor(s1, m, 64);
      s2 += __shfl_xor(s2, m, 64);
    }
    if (c == 0) { PS[w][4 * q + r] = s1; PQ[w][4 * q + r] = s2; }
  }
  __syncthreads();

#pragma unroll
  for (int r = 0; r < 4; ++r) {
    int row = 4 * q + r;
    float sum = PS[0][row] + PS[1][row] + PS[2][row] + PS[3][row];
    float sq  = PQ[0][row] + PQ[1][row] + PQ[2][row] + PQ[3][row];
    float mean = sum * (1.0f / 64.0f);
    float var = sq * (1.0f / 64.0f) - mean * mean;
    float hv = (S[r] - mean) * rsqrtf(var + 1e-5f) * lg + lb;
    hv = gelu_exact(hv);
    A[row * ASTR + n] = bsplit(hv);
  }
  __syncthreads();   // h fully written before cross-wave GEMM reads

  Frag h0 = load_afrag(A + c * ASTR + 8 * q);
  Frag h1 = load_afrag(A + c * ASTR + 32 + 8 * q);

  f32x4 hh = {0.f, 0.f, 0.f, 0.f};
  hh = mfma3(h0, n10, hh);
  hh = mfma3(h1, n11, hh);
#pragma unroll
  for (int r = 0; r < 4; ++r)
    hlf_out[(tilebase + 4 * q + r) * 64 + n] = (hh[r] + b1v) * gw4[r];  // wgt folded

  f32x4 hx = {0.f, 0.f, 0.f, 0.f};
  hx = mfma3(h0, nc0, hx);
  hx = mfma3(h1, nc1, hx);
  *(float4*)(x2T + n * M_NODES + tilebase + 4 * q) =
      make_float4(hx[0] + wcbv, hx[1] + wcbv, hx[2] + wcbv, hx[3] + wcbv);
}

// ---------------------------------------------------------------------------
// fused layer 2 + head
// ---------------------------------------------------------------------------
__global__ __launch_bounds__(256) void k_layer_last(
    const int* __restrict__ esrc, const float2* __restrict__ evw,
    const int* __restrict__ row_start,
    const float* __restrict__ hlf_in,
    const float* __restrict__ gw, const float* __restrict__ freq,
    const short* __restrict__ pw2, const float* __restrict__ b2,
    const float* __restrict__ lng, const float* __restrict__ lnb,
    const float* __restrict__ x2T,
    const short* __restrict__ pfc1, const float* __restrict__ fc1b,
    const float* __restrict__ fw2, const float* __restrict__ fb2,
    float* __restrict__ out)
{
  __shared__ unsigned int A[16 * ASTR];
  __shared__ float PS[4][16], PQ[4][16];
  const int tid = threadIdx.x, lane = tid & 63, w = tid >> 6;
  const int tilebase = blockIdx.x * 16;
  const int c = lane & 15, q = lane >> 4;
  const int n = 16 * w + c;

  float4 x2v = *(const float4*)(x2T + n * M_NODES + tilebase + 4 * q);
  float lg = lng[n], lb = lnb[n], vb = b2[n];

  EDGE_PHASE()

  Frag wb0 = load_bpk(pw2, 4096, n, 8 * q);
  Frag wb1 = load_bpk(pw2, 4096, n, 32 + 8 * q);
  __syncthreads();

  Frag a0 = load_afrag(A + c * ASTR + 8 * q);
  Frag a1 = load_afrag(A + c * ASTR + 32 + 8 * q);
  f32x4 acc = {0.f, 0.f, 0.f, 0.f};
  acc = mfma3(a0, wb0, acc);
  acc = mfma3(a1, wb1, acc);

  float S[4];
#pragma unroll
  for (int r = 0; r < 4; ++r) S[r] = acc[r] + vb + x2v[r];

#pragma unroll
  for (int r = 0; r < 4; ++r) {
    float s1 = S[r], s2 = S[r] * S[r];
#pragma unroll
    for (int m = 1; m < 16; m <<= 1) {
      s1 += __shfl_xor(s1, m, 64);
      s2 += __shfl_xor(s2, m, 64);
    }
    if (c == 0) { PS[w][4 * q + r] = s1; PQ[w][4 * q + r] = s2; }
  }
  __syncthreads();

#pragma unroll
  for (int r = 0; r < 4; ++r) {
    int row = 4 * q + r;
    float sum = PS[0][row] + PS[1][row] + PS[2][row] + PS[3][row];
    float sq  = PQ[0][row] + PQ[1][row] + PQ[2][row] + PQ[3][row];
    float mean = sum * (1.0f / 64.0f);
    float var = sq * (1.0f / 64.0f) - mean * mean;
    float hv = (S[r] - mean) * rsqrtf(var + 1e-5f) * lg + lb;   // no gelu
    A[row * ASTR + n] = bsplit(hv);
  }
  __syncthreads();

  // head: wave w covers fc1 rows 32w + {c, 16+c}
  Frag ha0 = load_afrag(A + c * ASTR + 8 * q);
  Frag ha1 = load_afrag(A + c * ASTR + 32 + 8 * q);
  float p[4] = {0.f, 0.f, 0.f, 0.f};
#pragma unroll
  for (int half = 0; half < 2; ++half) {
    int row = 32 * w + 16 * half + c;
    Frag b0 = load_bpk(pfc1, 8192, row, 8 * q);
    Frag b1 = load_bpk(pfc1, 8192, row, 32 + 8 * q);
    f32x4 a = {0.f, 0.f, 0.f, 0.f};
    a = mfma3(ha0, b0, a);
    a = mfma3(ha1, b1, a);
    float fbv = fc1b[row], fwv = fw2[row];
#pragma unroll
    for (int r = 0; r < 4; ++r) p[r] += gelu_exact(a[r] + fbv) * fwv;
  }
#pragma unroll
  for (int r = 0; r < 4; ++r) {
    float s = p[r];
#pragma unroll
    for (int m = 1; m < 16; m <<= 1) s += __shfl_xor(s, m, 64);
    if (c == 0) PS[w][4 * q + r] = s;
  }
  __syncthreads();
  if (tid < 16)
    out[tilebase + tid] = PS[0][tid] + PS[1][tid] + PS[2][tid] + PS[3][tid] + fb2[0];
}

// ---------------------------------------------------------------------------
extern "C" void kernel_launch(void* const* d_in, const int* in_sizes, int n_in,
                              void* d_out, int out_size, void* d_ws, size_t ws_size,
                              hipStream_t stream) {
  const float* x     = (const float*)d_in[0];
  const int* ei      = (const int*)d_in[1];
  const float* fc0_w = (const float*)d_in[2];
  const float* fc0_b = (const float*)d_in[3];
  const float* ln0_g = (const float*)d_in[4];
  const float* ln0_b = (const float*)d_in[5];
  const float* gg_fc1_w = (const float*)d_in[6];
  const float* gg_fc1_b = (const float*)d_in[7];
  const float* gg_fc2_w = (const float*)d_in[8];
  const float* gg_fc2_b = (const float*)d_in[9];
  const float* gg_weight = (const float*)d_in[10];
  const float* gg_freq   = (const float*)d_in[11];
  const float* wc_w = (const float*)d_in[12];
  const float* wc_b = (const float*)d_in[13];
  const float* ln_g = (const float*)d_in[14];
  const float* ln_b = (const float*)d_in[15];
  const float* fc1_w = (const float*)d_in[16];
  const float* fc1_b = (const float*)d_in[17];
  const float* fc2_w = (const float*)d_in[18];
  const float* fc2_b = (const float*)d_in[19];

  char* ws = (char*)d_ws;
  size_t off = 0;
  auto alloc = [&](size_t bytes) -> void* {
    void* p = ws + off;
    off = (off + bytes + 255) & ~(size_t)255;
    return p;
  };
  float2* grid2 = (float2*)alloc((size_t)M_NODES * 8);
  float*  gwf   = (float*)alloc((size_t)M_NODES * 4);
  float*  hlf_a = (float*)alloc((size_t)M_NODES * 64 * 4);
  float*  hlf_b = (float*)alloc((size_t)M_NODES * 64 * 4);
  float*  x2T   = (float*)alloc((size_t)M_NODES * 64 * 4);
  int*    cnt   = (int*)alloc((size_t)M_NODES * 4);
  int*    cursor= (int*)alloc((size_t)M_NODES * 4);
  int*    row_st= (int*)alloc((size_t)(M_NODES + 1) * 4);
  int*    esrc  = (int*)alloc((size_t)(E_EDGES + 1) * 4);
  float2* evw   = (float2*)alloc((size_t)(E_EDGES + 1) * 8);
  short*  pk    = (short*)alloc((size_t)PK_TOTAL * 2 * 2);
  (void)ws_size; (void)in_sizes; (void)n_in; (void)out_size;

  hipMemsetAsync(cnt, 0, (size_t)M_NODES * 4, stream);

  k_front<<<3248, 256, 0, stream>>>(x, fc0_w, fc0_b, ln0_g, ln0_b,
                                    gg_fc1_w, gg_fc1_b, wc_w, wc_b,
                                    gg_fc2_w, fc1_w,
                                    ei, cnt, pk, grid2, gwf, hlf_a, x2T);
  k_scan<<<1, 1024, 0, stream>>>(cnt, row_st, cursor, esrc, evw);
  k_scatter<<<E_EDGES / 256, 256, 0, stream>>>(ei, grid2, cursor, esrc, evw);

  // layer 0: read hlf_a -> write hlf_b
  k_layer_mid<<<M_NODES / 16, 256, 0, stream>>>(
      esrc, evw, row_st, hlf_a, gwf, gg_weight + 0 * 64, gg_freq + 0 * 128,
      pk + 2 * (PK_W2 + 0 * 4096), gg_fc2_b + 0 * 64,
      ln_g + 0 * 64, ln_b + 0 * 64,
      pk + 2 * (PK_W1 + 1 * 4096), gg_fc1_b + 1 * 64,
      pk + 2 * (PK_WC + 1 * 4096), wc_b + 1 * 64,
      hlf_b, x2T);
  // layer 1: read hlf_b -> write hlf_a
  k_layer_mid<<<M_NODES / 16, 256, 0, stream>>>(
      esrc, evw, row_st, hlf_b, gwf, gg_weight + 1 * 64, gg_freq + 1 * 128,
      pk + 2 * (PK_W2 + 1 * 4096), gg_fc2_b + 1 * 64,
      ln_g + 1 * 64, ln_b + 1 * 64,
      pk + 2 * (PK_W1 + 2 * 4096), gg_fc1_b + 2 * 64,
      pk + 2 * (PK_WC + 2 * 4096), wc_b + 2 * 64,
      hlf_a, x2T);
  // layer 2 + head: read hlf_a -> out
  k_layer_last<<<M_NODES / 16, 256, 0, stream>>>(
      esrc, evw, row_st, hlf_a, gg_weight + 2 * 64, gg_freq + 2 * 128,
      pk + 2 * (PK_W2 + 2 * 4096), gg_fc2_b + 2 * 64,
      ln_g + 2 * 64, ln_b + 2 * 64,
      x2T,
      pk + 2 * PK_FC1, fc1_b, fc2_w, fc2_b,
      (float*)d_out);
}